// Round 1
// baseline (110.404 us; speedup 1.0000x reference)
//
#include <hip/hip_runtime.h>

// out = relu((x @ B^T) * A^T + bias)  -- rank-1 reassociated form.
// x: [8192, 2048] f32, A: [10000,1] f32, B: [1,2048] f32, bias: [10000] f32
// out: [8192, 10000] f32

#define BATCH       8192
#define IN_FEATURES 2048
#define N_CLASSES   10000
#define NC4         (N_CLASSES / 4)   // 2500, exact
#define NF4         (IN_FEATURES / 4) // 512, exact
#define BLOCK       256

__global__ __launch_bounds__(BLOCK) void lora_cls_kernel(
    const float* __restrict__ x,
    const float* __restrict__ A,
    const float* __restrict__ B,
    const float* __restrict__ bias,
    float* __restrict__ out)
{
    const int row = blockIdx.x;
    const int tid = threadIdx.x;

    // ---- Phase 1: s = dot(x[row,:], B[0,:]) ----
    const float4* __restrict__ x4 = reinterpret_cast<const float4*>(x + (size_t)row * IN_FEATURES);
    const float4* __restrict__ B4 = reinterpret_cast<const float4*>(B);

    float acc = 0.0f;
    // 512 float4 per row / 256 threads = 2 per thread (coalesced)
    {
        float4 xa = x4[tid];
        float4 ba = B4[tid];
        float4 xb = x4[tid + BLOCK];
        float4 bb = B4[tid + BLOCK];
        acc = fmaf(xa.x, ba.x, acc);
        acc = fmaf(xa.y, ba.y, acc);
        acc = fmaf(xa.z, ba.z, acc);
        acc = fmaf(xa.w, ba.w, acc);
        acc = fmaf(xb.x, bb.x, acc);
        acc = fmaf(xb.y, bb.y, acc);
        acc = fmaf(xb.z, bb.z, acc);
        acc = fmaf(xb.w, bb.w, acc);
    }

    // wave-64 shuffle reduce
    #pragma unroll
    for (int off = 32; off > 0; off >>= 1)
        acc += __shfl_down(acc, off, 64);

    __shared__ float wsum[BLOCK / 64];
    __shared__ float s_bcast;
    const int lane = tid & 63;
    const int wid  = tid >> 6;
    if (lane == 0) wsum[wid] = acc;
    __syncthreads();
    if (tid == 0)
        s_bcast = wsum[0] + wsum[1] + wsum[2] + wsum[3];
    __syncthreads();
    const float s = s_bcast;

    // ---- Phase 2: out[row, j] = relu(s * A[j] + bias[j]) ----
    const float4* __restrict__ A4  = reinterpret_cast<const float4*>(A);
    const float4* __restrict__ bb4 = reinterpret_cast<const float4*>(bias);
    float4* __restrict__ o4 = reinterpret_cast<float4*>(out + (size_t)row * N_CLASSES);

    for (int j = tid; j < NC4; j += BLOCK) {
        float4 a = A4[j];
        float4 b = bb4[j];
        float4 r;
        r.x = fmaxf(fmaf(s, a.x, b.x), 0.0f);
        r.y = fmaxf(fmaf(s, a.y, b.y), 0.0f);
        r.z = fmaxf(fmaf(s, a.z, b.z), 0.0f);
        r.w = fmaxf(fmaf(s, a.w, b.w), 0.0f);
        o4[j] = r;
    }
}

extern "C" void kernel_launch(void* const* d_in, const int* in_sizes, int n_in,
                              void* d_out, int out_size, void* d_ws, size_t ws_size,
                              hipStream_t stream) {
    const float* x    = (const float*)d_in[0];
    const float* A    = (const float*)d_in[1];
    const float* B    = (const float*)d_in[2];
    const float* bias = (const float*)d_in[3];
    float* out        = (float*)d_out;

    lora_cls_kernel<<<BATCH, BLOCK, 0, stream>>>(x, A, B, bias, out);
}